// Round 1
// baseline (347.199 us; speedup 1.0000x reference)
//
#include <hip/hip_runtime.h>

#define HW    6400
#define CIN   256
#define HALF  128
#define QUART 64
#define NB    8
#define NE    5

// ---------------- Kernel A: pooled mean over H,W ----------------
__global__ void pool_kernel(const float* __restrict__ x, float* __restrict__ pooled) {
    int bc = blockIdx.x;                       // b*CIN + c
    const float* p = x + (size_t)bc * HW;
    float s = 0.f;
    for (int i = threadIdx.x; i < HW; i += 256) s += p[i];
    for (int off = 32; off > 0; off >>= 1) s += __shfl_down(s, off, 64);
    __shared__ float wsum[4];
    int wid = threadIdx.x >> 6, lane = threadIdx.x & 63;
    if (lane == 0) wsum[wid] = s;
    __syncthreads();
    if (threadIdx.x == 0)
        pooled[bc] = (wsum[0] + wsum[1] + wsum[2] + wsum[3]) * (1.0f / HW);
}

// ---------------- Kernel B: gate -> argmax expert per batch ----------------
__global__ void gate_kernel(const float* __restrict__ pooled, const float* __restrict__ Wg,
                            const float* __restrict__ bg, int* __restrict__ eidx) {
    int b = blockIdx.x;
    int lane = threadIdx.x;                    // 64 threads = 1 wave
    float pv[4];
#pragma unroll
    for (int j = 0; j < 4; ++j) pv[j] = pooled[b * CIN + lane * 4 + j];
    float best = -1e30f; int bi = 0;
    for (int e = 0; e < NE; ++e) {
        float part = 0.f;
#pragma unroll
        for (int j = 0; j < 4; ++j) part += pv[j] * Wg[e * CIN + lane * 4 + j];
        for (int off = 32; off > 0; off >>= 1) part += __shfl_down(part, off, 64);
        part = __shfl(part, 0, 64);
        float logit = part + bg[e];
        if (logit > best) { best = logit; bi = e; }   // strict > == first max (jnp.argmax)
    }
    if (lane == 0) eidx[b] = bi;
}

// ---------------- Kernel C: selected expert, 64-pixel tiles ----------------
__launch_bounds__(256, 2)
__global__ void expert_kernel(const float* __restrict__ x,
                              const float* __restrict__ Wrgb, const float* __restrict__ brgb,
                              const float* __restrict__ Wtir, const float* __restrict__ btir,
                              const float* __restrict__ Wt1,  const float* __restrict__ bt1,
                              const float* __restrict__ Wt2,  const float* __restrict__ bt2,
                              const int* __restrict__ eidx,   float* __restrict__ out) {
    __shared__ float buf0[HALF * 64];   // xr tile, then Dr tile
    __shared__ float buf1[HALF * 64];   // xt tile, then Dt tile
    __shared__ float hbuf[QUART * 64];  // h tile (r then t)

    const int b  = blockIdx.y;
    const int p0 = blockIdx.x * 64;
    const int e  = __builtin_amdgcn_readfirstlane(eidx[b]);
    const int t  = threadIdx.x;
    const int og = __builtin_amdgcn_readfirstlane(t >> 6);  // wave id, uniform
    const int p  = t & 63;

    // ---- stage x tile: 256 channels x 64 pixels, float4 loads ----
    const float* xb = x + (size_t)b * CIN * HW + p0;
#pragma unroll
    for (int i = 0; i < 16; ++i) {
        int g  = i * 256 + t;              // float4 index
        int c  = g >> 4;
        int p4 = (g & 15) * 4;
        float4 v = *reinterpret_cast<const float4*>(xb + (size_t)c * HW + p4);
        float* dst = (c < HALF ? buf0 + c * 64 : buf1 + (c - HALF) * 64) + p4;
        *reinterpret_cast<float4*>(dst) = v;
    }
    __syncthreads();

    const int ob = og * 32;
    float acc[32];

    // ---- Dr = xr + Wrgb[e] @ xr + brgb[e] ----
    {
        const float* W    = Wrgb + ((size_t)e * HALF + ob) * HALF;
        const float* bias = brgb + e * HALF + ob;
#pragma unroll
        for (int o = 0; o < 32; ++o) acc[o] = bias[o] + buf0[(ob + o) * 64 + p];
        for (int cb = 0; cb < HALF; cb += 16) {
            float xv[16];
#pragma unroll
            for (int j = 0; j < 16; ++j) xv[j] = buf0[(cb + j) * 64 + p];
#pragma unroll
            for (int o = 0; o < 32; ++o) {
                const float* wr = W + o * HALF + cb;
#pragma unroll
                for (int j = 0; j < 16; ++j) acc[o] = fmaf(wr[j], xv[j], acc[o]);
            }
        }
    }
    __syncthreads();                       // all Dr reads of buf0 done
#pragma unroll
    for (int o = 0; o < 32; ++o) buf0[(ob + o) * 64 + p] = acc[o];

    // ---- Dt = xt + Wtir[e] @ xt + btir[e] ----
    {
        const float* W    = Wtir + ((size_t)e * HALF + ob) * HALF;
        const float* bias = btir + e * HALF + ob;
#pragma unroll
        for (int o = 0; o < 32; ++o) acc[o] = bias[o] + buf1[(ob + o) * 64 + p];
        for (int cb = 0; cb < HALF; cb += 16) {
            float xv[16];
#pragma unroll
            for (int j = 0; j < 16; ++j) xv[j] = buf1[(cb + j) * 64 + p];
#pragma unroll
            for (int o = 0; o < 32; ++o) {
                const float* wr = W + o * HALF + cb;
#pragma unroll
                for (int j = 0; j < 16; ++j) acc[o] = fmaf(wr[j], xv[j], acc[o]);
            }
        }
    }
    __syncthreads();                       // Dt reads done; Dr (buf0) writes visible
#pragma unroll
    for (int o = 0; o < 32; ++o) buf1[(ob + o) * 64 + p] = acc[o];
    __syncthreads();                       // Dt (buf1) writes visible

    // ---- hr = relu(Wt1[e] @ Dr + bt1[e]) ----
    const int mb = og * 16;
    {
        const float* W    = Wt1 + ((size_t)e * QUART + mb) * HALF;
        const float* bias = bt1 + e * QUART + mb;
        float hm[16];
#pragma unroll
        for (int m = 0; m < 16; ++m) hm[m] = bias[m];
        for (int cb = 0; cb < HALF; cb += 16) {
            float xv[16];
#pragma unroll
            for (int j = 0; j < 16; ++j) xv[j] = buf0[(cb + j) * 64 + p];
#pragma unroll
            for (int m = 0; m < 16; ++m) {
                const float* wr = W + m * HALF + cb;
#pragma unroll
                for (int j = 0; j < 16; ++j) hm[m] = fmaf(wr[j], xv[j], hm[m]);
            }
        }
#pragma unroll
        for (int m = 0; m < 16; ++m) hbuf[(mb + m) * 64 + p] = fmaxf(hm[m], 0.f);
    }
    __syncthreads();

    // ---- ar, sigmoid (redundant per og-group, 64 MACs) ----
    float ar = bt2[e];
    {
        const float* W = Wt2 + (size_t)e * QUART;
#pragma unroll
        for (int m = 0; m < QUART; ++m) ar = fmaf(W[m], hbuf[m * 64 + p], ar);
    }
    float sr = 1.f / (1.f + __expf(-ar));
    __syncthreads();                       // hr reads done before overwrite

    // ---- ht = relu(Wt1[e] @ Dt + bt1[e]) ----
    {
        const float* W    = Wt1 + ((size_t)e * QUART + mb) * HALF;
        const float* bias = bt1 + e * QUART + mb;
        float hm[16];
#pragma unroll
        for (int m = 0; m < 16; ++m) hm[m] = bias[m];
        for (int cb = 0; cb < HALF; cb += 16) {
            float xv[16];
#pragma unroll
            for (int j = 0; j < 16; ++j) xv[j] = buf1[(cb + j) * 64 + p];
#pragma unroll
            for (int m = 0; m < 16; ++m) {
                const float* wr = W + m * HALF + cb;
#pragma unroll
                for (int j = 0; j < 16; ++j) hm[m] = fmaf(wr[j], xv[j], hm[m]);
            }
        }
#pragma unroll
        for (int m = 0; m < 16; ++m) hbuf[(mb + m) * 64 + p] = fmaxf(hm[m], 0.f);
    }
    __syncthreads();

    float at = bt2[e];
    {
        const float* W = Wt2 + (size_t)e * QUART;
#pragma unroll
        for (int m = 0; m < QUART; ++m) at = fmaf(W[m], hbuf[m * 64 + p], at);
    }
    float st = 1.f / (1.f + __expf(-at));

    // ---- out = sr*Dr + st*Dt ----
    float* op = out + ((size_t)b * HALF + ob) * HW + p0 + p;
#pragma unroll
    for (int o = 0; o < 32; ++o)
        op[(size_t)o * HW] = sr * buf0[(ob + o) * 64 + p] + st * buf1[(ob + o) * 64 + p];
}

extern "C" void kernel_launch(void* const* d_in, const int* in_sizes, int n_in,
                              void* d_out, int out_size, void* d_ws, size_t ws_size,
                              hipStream_t stream) {
    const float* x    = (const float*)d_in[0];
    const float* Wg   = (const float*)d_in[1];
    const float* bg   = (const float*)d_in[2];
    const float* Wrgb = (const float*)d_in[3];
    const float* brgb = (const float*)d_in[4];
    const float* Wtir = (const float*)d_in[5];
    const float* btir = (const float*)d_in[6];
    const float* Wt1  = (const float*)d_in[7];
    const float* bt1  = (const float*)d_in[8];
    const float* Wt2  = (const float*)d_in[9];
    const float* bt2  = (const float*)d_in[10];
    float* out   = (float*)d_out;
    float* pooled = (float*)d_ws;                     // 2048 floats
    int*   eidx   = (int*)((char*)d_ws + 8192);       // 8 ints

    pool_kernel<<<NB * CIN, 256, 0, stream>>>(x, pooled);
    gate_kernel<<<NB, 64, 0, stream>>>(pooled, Wg, bg, eidx);
    dim3 grid(100, NB);
    expert_kernel<<<grid, 256, 0, stream>>>(x, Wrgb, brgb, Wtir, btir,
                                            Wt1, bt1, Wt2, bt2, eidx, out);
}

// Round 2
// 140.047 us; speedup vs baseline: 2.4792x; 2.4792x over previous
//
#include <hip/hip_runtime.h>

#define HW    6400
#define CIN   256
#define HALF  128
#define QUART 64
#define NB    8
#define NE    5

typedef __attribute__((ext_vector_type(8))) short short8;
typedef __attribute__((ext_vector_type(4))) float f32x4;

__device__ __forceinline__ unsigned short f2bf(float f) {
    unsigned u = __builtin_bit_cast(unsigned, f);
    u = (u + 0x7FFFu + ((u >> 16) & 1u)) >> 16;   // RNE
    return (unsigned short)u;
}
__device__ __forceinline__ float bf2f(unsigned short h) {
    unsigned u = ((unsigned)h) << 16;
    return __builtin_bit_cast(float, u);
}

// ---------------- prep: fp32 weights -> bf16 in workspace ----------------
// bw layout (shorts): [0,81920) Wrgb  [81920,163840) Wtir  [163840,204800) Wt1
__global__ void prep_kernel(const float* __restrict__ Wrgb, const float* __restrict__ Wtir,
                            const float* __restrict__ Wt1, unsigned short* __restrict__ bw) {
    for (int i = blockIdx.x * 256 + threadIdx.x; i < 204800; i += gridDim.x * 256) {
        float v;
        if (i < 81920)       v = Wrgb[i];
        else if (i < 163840) v = Wtir[i - 81920];
        else                 v = Wt1[i - 163840];
        bw[i] = f2bf(v);
    }
}

// ---------------- pool: mean over H,W ----------------
__global__ void pool_kernel(const float* __restrict__ x, float* __restrict__ pooled) {
    int bc = blockIdx.x;
    const float4* p = reinterpret_cast<const float4*>(x + (size_t)bc * HW);
    float s = 0.f;
    for (int i = threadIdx.x; i < HW / 4; i += 256) {
        float4 v = p[i];
        s += (v.x + v.y) + (v.z + v.w);
    }
    for (int off = 32; off > 0; off >>= 1) s += __shfl_down(s, off, 64);
    __shared__ float wsum[4];
    int wid = threadIdx.x >> 6, lane = threadIdx.x & 63;
    if (lane == 0) wsum[wid] = s;
    __syncthreads();
    if (threadIdx.x == 0)
        pooled[bc] = (wsum[0] + wsum[1] + wsum[2] + wsum[3]) * (1.0f / HW);
}

// ---------------- gate: argmax expert per batch ----------------
__global__ void gate_kernel(const float* __restrict__ pooled, const float* __restrict__ Wg,
                            const float* __restrict__ bg, int* __restrict__ eidx) {
    int b = blockIdx.x;
    int lane = threadIdx.x;                    // 64 threads = 1 wave
    float pv[4];
#pragma unroll
    for (int j = 0; j < 4; ++j) pv[j] = pooled[b * CIN + lane * 4 + j];
    float best = -1e30f; int bi = 0;
    for (int e = 0; e < NE; ++e) {
        float part = 0.f;
#pragma unroll
        for (int j = 0; j < 4; ++j) part += pv[j] * Wg[e * CIN + lane * 4 + j];
        for (int off = 32; off > 0; off >>= 1) part += __shfl_down(part, off, 64);
        part = __shfl(part, 0, 64);
        float logit = part + bg[e];
        if (logit > best) { best = logit; bi = e; }   // strict > == first max (jnp.argmax)
    }
    if (lane == 0) eidx[b] = bi;
}

// ---------------- expert: MFMA, 64-pixel tiles ----------------
// LDS frag-linear layout for a 128ch x 64px bf16 tile:
//   frag f = kt*4 + pt  (kt = ch>>5, pt = px>>4), 1 KiB per frag
//   within frag: lane l = ((ch>>3)&3)*16 + (px&15) holds ch = kt*32+8*((ch>>3)&3)+e
//   byte addr = f*1024 + l*16 + (ch&7)*2  -> B-frag ds_read_b128 at lane*16: conflict-free
__launch_bounds__(256, 3)
__global__ void expert_kernel(const float* __restrict__ x,
                              const unsigned short* __restrict__ bW,
                              const float* __restrict__ brgb, const float* __restrict__ btir,
                              const float* __restrict__ bt1,
                              const float* __restrict__ Wt2, const float* __restrict__ bt2,
                              const int* __restrict__ eidx, float* __restrict__ out) {
    __shared__ unsigned short lxr[8192];   // 16 KiB: xr tile, later Dr (bf16)
    __shared__ unsigned short lxt[8192];   // 16 KiB: xt tile, later Dt (bf16)
    __shared__ float lh[64 * 68];          // 17 KiB: h tile, px-major, pad->16B-aligned rows
    __shared__ float psum[256];
    __shared__ float sfin[128];            // sigmoid r [0,64) / t [64,128)

    const int b    = blockIdx.y;
    const int p0   = blockIdx.x * 64;
    const int e    = __builtin_amdgcn_readfirstlane(eidx[b]);
    const int t    = threadIdx.x;
    const int w    = __builtin_amdgcn_readfirstlane(t >> 6);
    const int lane = t & 63;
    const int lo   = lane & 15, hi = lane >> 4;

    const unsigned short* bWrgb = bW + (size_t)e * 16384;
    const unsigned short* bWtir = bW + 81920 + (size_t)e * 16384;
    const unsigned short* bWt1  = bW + 163840 + (size_t)e * 8192;

    // ---- stage x -> bf16 frag-linear LDS (both halves) ----
    {
        const int px = t & 63, cb = t >> 6;            // cb = kt block of 32 ch
        const float* xb = x + (size_t)b * CIN * HW + p0 + px;
        const int li = (px & 15) * 8;
        const int fb = (cb * 4 + (px >> 4)) * 512;
#pragma unroll
        for (int jg = 0; jg < 4; ++jg) {
            unsigned vr[4], vt[4];
#pragma unroll
            for (int jp = 0; jp < 4; ++jp) {
                int ch = cb * 32 + jg * 8 + jp * 2;
                float r0 = xb[(size_t)ch * HW];
                float r1 = xb[(size_t)(ch + 1) * HW];
                float t0 = xb[(size_t)(ch + HALF) * HW];
                float t1 = xb[(size_t)(ch + HALF + 1) * HW];
                vr[jp] = (unsigned)f2bf(r0) | ((unsigned)f2bf(r1) << 16);
                vt[jp] = (unsigned)f2bf(t0) | ((unsigned)f2bf(t1) << 16);
            }
            int si = fb + jg * 128 + li;
            *reinterpret_cast<uint4*>(&lxr[si]) = make_uint4(vr[0], vr[1], vr[2], vr[3]);
            *reinterpret_cast<uint4*>(&lxt[si]) = make_uint4(vt[0], vt[1], vt[2], vt[3]);
        }
    }
    __syncthreads();

    // ---- Dr = Wrgb[e]@xr, Dt = Wtir[e]@xt  (fused k-loop) ----
    f32x4 cr[2][4], ct[2][4];
    {
        f32x4 z = {0.f, 0.f, 0.f, 0.f};
#pragma unroll
        for (int i = 0; i < 2; ++i)
#pragma unroll
            for (int j = 0; j < 4; ++j) { cr[i][j] = z; ct[i][j] = z; }
    }
#pragma unroll
    for (int kt = 0; kt < 4; ++kt) {
        short8 bR[4], bT[4];
#pragma unroll
        for (int pt = 0; pt < 4; ++pt) {
            bR[pt] = *reinterpret_cast<const short8*>(&lxr[(kt * 4 + pt) * 512 + lane * 8]);
            bT[pt] = *reinterpret_cast<const short8*>(&lxt[(kt * 4 + pt) * 512 + lane * 8]);
        }
#pragma unroll
        for (int rt = 0; rt < 2; ++rt) {
            int row = w * 32 + rt * 16 + lo;
            short8 aR = *reinterpret_cast<const short8*>(&bWrgb[row * 128 + kt * 32 + hi * 8]);
            short8 aT = *reinterpret_cast<const short8*>(&bWtir[row * 128 + kt * 32 + hi * 8]);
#pragma unroll
            for (int pt = 0; pt < 4; ++pt) {
                cr[rt][pt] = __builtin_amdgcn_mfma_f32_16x16x32_bf16(aR, bR[pt], cr[rt][pt], 0, 0, 0);
                ct[rt][pt] = __builtin_amdgcn_mfma_f32_16x16x32_bf16(aT, bT[pt], ct[rt][pt], 0, 0, 0);
            }
        }
    }

    // ---- D += x + bias (fp32 in regs), pack bf16 for LDS round-trip ----
    uint2 dbr[2][4], dbt[2][4];
#pragma unroll
    for (int rt = 0; rt < 2; ++rt) {
        int r0c = w * 32 + rt * 16 + hi * 4;           // 4 consecutive rows (regs)
        f32x4 biasR = *reinterpret_cast<const f32x4*>(&brgb[e * HALF + r0c]);
        f32x4 biasT = *reinterpret_cast<const f32x4*>(&btir[e * HALF + r0c]);
        int kt2 = r0c >> 5;
        int lp8 = (((r0c >> 3) & 3) * 16 + lo) * 8 + (r0c & 7);
#pragma unroll
        for (int pt = 0; pt < 4; ++pt) {
            int si = (kt2 * 4 + pt) * 512 + lp8;
            ushort4 xr4 = *reinterpret_cast<const ushort4*>(&lxr[si]);
            ushort4 xt4 = *reinterpret_cast<const ushort4*>(&lxt[si]);
            float xrv[4] = {bf2f(xr4.x), bf2f(xr4.y), bf2f(xr4.z), bf2f(xr4.w)};
            float xtv[4] = {bf2f(xt4.x), bf2f(xt4.y), bf2f(xt4.z), bf2f(xt4.w)};
#pragma unroll
            for (int rg = 0; rg < 4; ++rg) {
                cr[rt][pt][rg] += biasR[rg] + xrv[rg];
                ct[rt][pt][rg] += biasT[rg] + xtv[rg];
            }
            dbr[rt][pt] = make_uint2(
                (unsigned)f2bf(cr[rt][pt][0]) | ((unsigned)f2bf(cr[rt][pt][1]) << 16),
                (unsigned)f2bf(cr[rt][pt][2]) | ((unsigned)f2bf(cr[rt][pt][3]) << 16));
            dbt[rt][pt] = make_uint2(
                (unsigned)f2bf(ct[rt][pt][0]) | ((unsigned)f2bf(ct[rt][pt][1]) << 16),
                (unsigned)f2bf(ct[rt][pt][2]) | ((unsigned)f2bf(ct[rt][pt][3]) << 16));
        }
    }
    __syncthreads();                                   // all x reads done
#pragma unroll
    for (int rt = 0; rt < 2; ++rt) {
        int r0c = w * 32 + rt * 16 + hi * 4;
        int kt2 = r0c >> 5;
        int lp8 = (((r0c >> 3) & 3) * 16 + lo) * 8 + (r0c & 7);
#pragma unroll
        for (int pt = 0; pt < 4; ++pt) {
            int si = (kt2 * 4 + pt) * 512 + lp8;
            *reinterpret_cast<uint2*>(&lxr[si]) = dbr[rt][pt];
            *reinterpret_cast<uint2*>(&lxt[si]) = dbt[rt][pt];
        }
    }
    __syncthreads();                                   // Dr/Dt bf16 visible

    // ---- phase r then t: h = relu(Wt1@D + bt1); a = Wt2@h + bt2; s = sigmoid ----
#pragma unroll
    for (int ph = 0; ph < 2; ++ph) {
        const unsigned short* lD = ph == 0 ? lxr : lxt;
        f32x4 chv[4];
        {
            f32x4 z = {0.f, 0.f, 0.f, 0.f};
#pragma unroll
            for (int j = 0; j < 4; ++j) chv[j] = z;
        }
#pragma unroll
        for (int kt = 0; kt < 4; ++kt) {
            int row = w * 16 + lo;
            short8 aH = *reinterpret_cast<const short8*>(&bWt1[row * 128 + kt * 32 + hi * 8]);
#pragma unroll
            for (int pt = 0; pt < 4; ++pt) {
                short8 bD = *reinterpret_cast<const short8*>(&lD[(kt * 4 + pt) * 512 + lane * 8]);
                chv[pt] = __builtin_amdgcn_mfma_f32_16x16x32_bf16(aH, bD, chv[pt], 0, 0, 0);
            }
        }
        int m0 = w * 16 + hi * 4;
        f32x4 b1 = *reinterpret_cast<const f32x4*>(&bt1[e * QUART + m0]);
#pragma unroll
        for (int pt = 0; pt < 4; ++pt) {
            f32x4 hv;
#pragma unroll
            for (int rg = 0; rg < 4; ++rg) hv[rg] = fmaxf(chv[pt][rg] + b1[rg], 0.f);
            int pxw = pt * 16 + lo;
            *reinterpret_cast<f32x4*>(&lh[pxw * 68 + m0]) = hv;
        }
        __syncthreads();
        {
            int pxa = t & 63, m0a = (t >> 6) * 16;
            const float* w2 = Wt2 + e * QUART + m0a;
            const float* hp = &lh[pxa * 68 + m0a];
            float s16 = 0.f;
#pragma unroll
            for (int j = 0; j < 16; ++j) s16 += w2[j] * hp[j];
            psum[(t >> 6) * 64 + pxa] = s16;
        }
        __syncthreads();
        if (t < 64) {
            float a = psum[t] + psum[64 + t] + psum[128 + t] + psum[192 + t] + bt2[e];
            sfin[ph * 64 + t] = 1.f / (1.f + __expf(-a));
        }
        __syncthreads();                               // sfin ready; lh free for next phase
    }

    // ---- out = s_r*Dr + s_t*Dt ----
#pragma unroll
    for (int rt = 0; rt < 2; ++rt) {
        int r0c = w * 32 + rt * 16 + hi * 4;
#pragma unroll
        for (int pt = 0; pt < 4; ++pt) {
            int pxb = pt * 16 + lo;
            float sr = sfin[pxb], st = sfin[64 + pxb];
            float* op = out + ((size_t)b * HALF + r0c) * HW + p0 + pxb;
#pragma unroll
            for (int rg = 0; rg < 4; ++rg)
                op[(size_t)rg * HW] = sr * cr[rt][pt][rg] + st * ct[rt][pt][rg];
        }
    }
}

extern "C" void kernel_launch(void* const* d_in, const int* in_sizes, int n_in,
                              void* d_out, int out_size, void* d_ws, size_t ws_size,
                              hipStream_t stream) {
    const float* x    = (const float*)d_in[0];
    const float* Wg   = (const float*)d_in[1];
    const float* bg   = (const float*)d_in[2];
    const float* Wrgb = (const float*)d_in[3];
    const float* brgb = (const float*)d_in[4];
    const float* Wtir = (const float*)d_in[5];
    const float* btir = (const float*)d_in[6];
    const float* Wt1  = (const float*)d_in[7];
    const float* bt1  = (const float*)d_in[8];
    const float* Wt2  = (const float*)d_in[9];
    const float* bt2  = (const float*)d_in[10];
    float* out = (float*)d_out;

    float*          pooled = (float*)d_ws;                              // 8 KiB
    int*            eidx   = (int*)((char*)d_ws + 8192);                // 32 B
    unsigned short* bw     = (unsigned short*)((char*)d_ws + 8448);     // 400 KiB bf16 weights

    prep_kernel<<<200, 256, 0, stream>>>(Wrgb, Wtir, Wt1, bw);
    pool_kernel<<<NB * CIN, 256, 0, stream>>>(x, pooled);
    gate_kernel<<<NB, 64, 0, stream>>>(pooled, Wg, bg, eidx);
    dim3 grid(100, NB);
    expert_kernel<<<grid, 256, 0, stream>>>(x, bw, brgb, btir, bt1, Wt2, bt2, eidx, out);
}

// Round 3
// 132.965 us; speedup vs baseline: 2.6112x; 1.0533x over previous
//
#include <hip/hip_runtime.h>

#define HW    6400
#define CIN   256
#define HALF  128
#define QUART 64
#define NB    8
#define NE    5

typedef __attribute__((ext_vector_type(8))) short short8;
typedef __attribute__((ext_vector_type(4))) float f32x4;

__device__ __forceinline__ unsigned short f2bf(float f) {
    unsigned u = __builtin_bit_cast(unsigned, f);
    u = (u + 0x7FFFu + ((u >> 16) & 1u)) >> 16;   // RNE
    return (unsigned short)u;
}

// ---------------- kernel 1: pool (blocks 0..2047) + bf16 weight prep (2048..2247) ----
// bw layout (shorts): [0,81920) Wrgb+I  [81920,163840) Wtir+I  [163840,204800) Wt1
__global__ void pool_prep_kernel(const float* __restrict__ x,
                                 const float* __restrict__ Wrgb, const float* __restrict__ Wtir,
                                 const float* __restrict__ Wt1,
                                 float* __restrict__ pooled, unsigned short* __restrict__ bw) {
    int blk = blockIdx.x;
    if (blk < NB * CIN) {
        const float4* p = reinterpret_cast<const float4*>(x + (size_t)blk * HW);
        float s = 0.f;
        for (int i = threadIdx.x; i < HW / 4; i += 256) {
            float4 v = p[i];
            s += (v.x + v.y) + (v.z + v.w);
        }
        for (int off = 32; off > 0; off >>= 1) s += __shfl_down(s, off, 64);
        __shared__ float wsum[4];
        int wid = threadIdx.x >> 6, lane = threadIdx.x & 63;
        if (lane == 0) wsum[wid] = s;
        __syncthreads();
        if (threadIdx.x == 0)
            pooled[blk] = (wsum[0] + wsum[1] + wsum[2] + wsum[3]) * (1.0f / HW);
    } else {
        int i0 = (blk - NB * CIN) * 1024 + threadIdx.x;
#pragma unroll
        for (int j = 0; j < 4; ++j) {
            int i = i0 + j * 256;
            float v;
            if (i < 81920) {                      // Wrgb + I
                v = Wrgb[i];
                int m = i & 16383;
                if ((m >> 7) == (m & 127)) v += 1.0f;
            } else if (i < 163840) {              // Wtir + I
                int k = i - 81920;
                v = Wtir[k];
                int m = k & 16383;
                if ((m >> 7) == (m & 127)) v += 1.0f;
            } else {
                v = Wt1[i - 163840];
            }
            bw[i] = f2bf(v);
        }
    }
}

// ---------------- kernel 2: gate (per-block, wave 0) + selected-expert MFMA ----------
// LDS frag-linear layout per 128ch x 64px bf16 tile:
//   frag f = kt*4 + pt (kt=ch>>5, pt=px>>4), 1 KiB/frag;
//   lane l = ((ch>>3)&3)*16 + (px&15); byte = f*1024 + l*16 + (ch&7)*2
//   -> B-frag ds_read_b128 at lane*16: conflict-free.
__launch_bounds__(256, 4)
__global__ void expert_kernel(const float* __restrict__ x,
                              const unsigned short* __restrict__ bW,
                              const float* __restrict__ brgb, const float* __restrict__ btir,
                              const float* __restrict__ bt1,
                              const float* __restrict__ Wt2, const float* __restrict__ bt2,
                              const float* __restrict__ pooled,
                              const float* __restrict__ Wg, const float* __restrict__ bg,
                              float* __restrict__ out) {
    __shared__ unsigned short lxr[8192];   // 16 KiB: xr tile -> Dr bf16
    __shared__ unsigned short lxt[8192];   // 16 KiB: xt tile -> Dt bf16
    __shared__ float psum[512];            // wave partials: [ph*256 + w*64 + px]
    __shared__ float sfin[128];            // sigmoid r [0,64) / t [64,128)
    __shared__ int   se;

    const int b    = blockIdx.y;
    const int p0   = blockIdx.x * 64;
    const int t    = threadIdx.x;
    const int w    = __builtin_amdgcn_readfirstlane(t >> 6);
    const int lane = t & 63;
    const int lo   = lane & 15, hi = lane >> 4;

    // ---- stage x -> bf16 frag-linear LDS (both halves) ----
    {
        const int px = t & 63, cb = t >> 6;
        const float* xb = x + (size_t)b * CIN * HW + p0 + px;
        const int li = (px & 15) * 8;
        const int fb = (cb * 4 + (px >> 4)) * 512;
#pragma unroll
        for (int jg = 0; jg < 4; ++jg) {
            unsigned vr[4], vt[4];
#pragma unroll
            for (int jp = 0; jp < 4; ++jp) {
                int ch = cb * 32 + jg * 8 + jp * 2;
                float r0 = xb[(size_t)ch * HW];
                float r1 = xb[(size_t)(ch + 1) * HW];
                float t0 = xb[(size_t)(ch + HALF) * HW];
                float t1 = xb[(size_t)(ch + HALF + 1) * HW];
                vr[jp] = (unsigned)f2bf(r0) | ((unsigned)f2bf(r1) << 16);
                vt[jp] = (unsigned)f2bf(t0) | ((unsigned)f2bf(t1) << 16);
            }
            int si = fb + jg * 128 + li;
            *reinterpret_cast<uint4*>(&lxr[si]) = make_uint4(vr[0], vr[1], vr[2], vr[3]);
            *reinterpret_cast<uint4*>(&lxt[si]) = make_uint4(vt[0], vt[1], vt[2], vt[3]);
        }
    }

    // ---- gate on wave 0 (redundant per block; L2-hot inputs) ----
    if (t < 64) {
        float pv[4];
#pragma unroll
        for (int j = 0; j < 4; ++j) pv[j] = pooled[b * CIN + t * 4 + j];
        float best = -1e30f; int bi = 0;
        for (int e = 0; e < NE; ++e) {
            float part = 0.f;
#pragma unroll
            for (int j = 0; j < 4; ++j) part += pv[j] * Wg[e * CIN + t * 4 + j];
            for (int off = 32; off > 0; off >>= 1) part += __shfl_down(part, off, 64);
            part = __shfl(part, 0, 64);
            float logit = part + bg[e];
            if (logit > best) { best = logit; bi = e; }  // strict > == jnp.argmax
        }
        if (t == 0) se = bi;
    }
    __syncthreads();

    const int e = __builtin_amdgcn_readfirstlane(se);
    const unsigned short* bWrgb = bW + (size_t)e * 16384;
    const unsigned short* bWtir = bW + 81920 + (size_t)e * 16384;
    const unsigned short* bWt1  = bW + 163840 + (size_t)e * 8192;

    // ---- Dr = (Wrgb+I)@xr, Dt = (Wtir+I)@xt ----
    f32x4 cr[2][4], ct[2][4];
    {
        f32x4 z = {0.f, 0.f, 0.f, 0.f};
#pragma unroll
        for (int i = 0; i < 2; ++i)
#pragma unroll
            for (int j = 0; j < 4; ++j) { cr[i][j] = z; ct[i][j] = z; }
    }
#pragma unroll
    for (int kt = 0; kt < 4; ++kt) {
        short8 bR[4], bT[4];
#pragma unroll
        for (int pt = 0; pt < 4; ++pt) {
            bR[pt] = *reinterpret_cast<const short8*>(&lxr[(kt * 4 + pt) * 512 + lane * 8]);
            bT[pt] = *reinterpret_cast<const short8*>(&lxt[(kt * 4 + pt) * 512 + lane * 8]);
        }
#pragma unroll
        for (int rt = 0; rt < 2; ++rt) {
            int row = w * 32 + rt * 16 + lo;
            short8 aR = *reinterpret_cast<const short8*>(&bWrgb[row * 128 + kt * 32 + hi * 8]);
            short8 aT = *reinterpret_cast<const short8*>(&bWtir[row * 128 + kt * 32 + hi * 8]);
#pragma unroll
            for (int pt = 0; pt < 4; ++pt) {
                cr[rt][pt] = __builtin_amdgcn_mfma_f32_16x16x32_bf16(aR, bR[pt], cr[rt][pt], 0, 0, 0);
                ct[rt][pt] = __builtin_amdgcn_mfma_f32_16x16x32_bf16(aT, bT[pt], ct[rt][pt], 0, 0, 0);
            }
        }
    }

    // ---- D += bias (fp32), pack bf16 ----
    uint2 dbr[2][4], dbt[2][4];
#pragma unroll
    for (int rt = 0; rt < 2; ++rt) {
        int r0c = w * 32 + rt * 16 + hi * 4;
        f32x4 biasR = *reinterpret_cast<const f32x4*>(&brgb[e * HALF + r0c]);
        f32x4 biasT = *reinterpret_cast<const f32x4*>(&btir[e * HALF + r0c]);
#pragma unroll
        for (int pt = 0; pt < 4; ++pt) {
#pragma unroll
            for (int rg = 0; rg < 4; ++rg) {
                cr[rt][pt][rg] += biasR[rg];
                ct[rt][pt][rg] += biasT[rg];
            }
            dbr[rt][pt] = make_uint2(
                (unsigned)f2bf(cr[rt][pt][0]) | ((unsigned)f2bf(cr[rt][pt][1]) << 16),
                (unsigned)f2bf(cr[rt][pt][2]) | ((unsigned)f2bf(cr[rt][pt][3]) << 16));
            dbt[rt][pt] = make_uint2(
                (unsigned)f2bf(ct[rt][pt][0]) | ((unsigned)f2bf(ct[rt][pt][1]) << 16),
                (unsigned)f2bf(ct[rt][pt][2]) | ((unsigned)f2bf(ct[rt][pt][3]) << 16));
        }
    }
    __syncthreads();                                   // all GEMM1 B-frag reads done
#pragma unroll
    for (int rt = 0; rt < 2; ++rt) {
        int r0c = w * 32 + rt * 16 + hi * 4;
        int kt2 = r0c >> 5;
        int lp8 = (((r0c >> 3) & 3) * 16 + lo) * 8 + (r0c & 7);
#pragma unroll
        for (int pt = 0; pt < 4; ++pt) {
            int si = (kt2 * 4 + pt) * 512 + lp8;
            *reinterpret_cast<uint2*>(&lxr[si]) = dbr[rt][pt];
            *reinterpret_cast<uint2*>(&lxt[si]) = dbt[rt][pt];
        }
    }
    __syncthreads();                                   // Dr/Dt bf16 visible

    // ---- h = relu(Wt1@D + bt1) for both halves, fragments in registers ----
    f32x4 chr[4], cht[4];
    {
        f32x4 z = {0.f, 0.f, 0.f, 0.f};
#pragma unroll
        for (int j = 0; j < 4; ++j) { chr[j] = z; cht[j] = z; }
    }
#pragma unroll
    for (int kt = 0; kt < 4; ++kt) {
        int row = w * 16 + lo;
        short8 aH = *reinterpret_cast<const short8*>(&bWt1[row * 128 + kt * 32 + hi * 8]);
#pragma unroll
        for (int pt = 0; pt < 4; ++pt) {
            short8 bDr = *reinterpret_cast<const short8*>(&lxr[(kt * 4 + pt) * 512 + lane * 8]);
            short8 bDt = *reinterpret_cast<const short8*>(&lxt[(kt * 4 + pt) * 512 + lane * 8]);
            chr[pt] = __builtin_amdgcn_mfma_f32_16x16x32_bf16(aH, bDr, chr[pt], 0, 0, 0);
            cht[pt] = __builtin_amdgcn_mfma_f32_16x16x32_bf16(aH, bDt, cht[pt], 0, 0, 0);
        }
    }

    // ---- Wt2·h in-register: 4 FMA + butterfly over hi, psum over waves ----
    {
        int m0 = w * 16 + hi * 4;
        f32x4 b1  = *reinterpret_cast<const f32x4*>(&bt1[e * QUART + m0]);
        f32x4 w2v = *reinterpret_cast<const f32x4*>(&Wt2[e * QUART + m0]);
#pragma unroll
        for (int pt = 0; pt < 4; ++pt) {
            float pr = 0.f, ptt = 0.f;
#pragma unroll
            for (int rg = 0; rg < 4; ++rg) {
                pr  = fmaf(w2v[rg], fmaxf(chr[pt][rg] + b1[rg], 0.f), pr);
                ptt = fmaf(w2v[rg], fmaxf(cht[pt][rg] + b1[rg], 0.f), ptt);
            }
            pr  += __shfl_xor(pr, 16, 64);  pr  += __shfl_xor(pr, 32, 64);
            ptt += __shfl_xor(ptt, 16, 64); ptt += __shfl_xor(ptt, 32, 64);
            if (hi == 0) {
                psum[w * 64 + pt * 16 + lo]       = pr;
                psum[256 + w * 64 + pt * 16 + lo] = ptt;
            }
        }
    }
    __syncthreads();
    if (t < 128) {
        int ph = t >> 6, px = t & 63;
        const float* ps = &psum[ph * 256];
        float a = ps[px] + ps[64 + px] + ps[128 + px] + ps[192 + px] + bt2[e];
        sfin[t] = 1.f / (1.f + __expf(-a));
    }
    __syncthreads();

    // ---- out = s_r*Dr + s_t*Dt (D fp32 still in accumulators) ----
#pragma unroll
    for (int rt = 0; rt < 2; ++rt) {
        int r0c = w * 32 + rt * 16 + hi * 4;
#pragma unroll
        for (int pt = 0; pt < 4; ++pt) {
            int pxb = pt * 16 + lo;
            float sr = sfin[pxb], st = sfin[64 + pxb];
            float* op = out + ((size_t)b * HALF + r0c) * HW + p0 + pxb;
#pragma unroll
            for (int rg = 0; rg < 4; ++rg)
                op[(size_t)rg * HW] = sr * cr[rt][pt][rg] + st * ct[rt][pt][rg];
        }
    }
}

extern "C" void kernel_launch(void* const* d_in, const int* in_sizes, int n_in,
                              void* d_out, int out_size, void* d_ws, size_t ws_size,
                              hipStream_t stream) {
    const float* x    = (const float*)d_in[0];
    const float* Wg   = (const float*)d_in[1];
    const float* bg   = (const float*)d_in[2];
    const float* Wrgb = (const float*)d_in[3];
    const float* brgb = (const float*)d_in[4];
    const float* Wtir = (const float*)d_in[5];
    const float* btir = (const float*)d_in[6];
    const float* Wt1  = (const float*)d_in[7];
    const float* bt1  = (const float*)d_in[8];
    const float* Wt2  = (const float*)d_in[9];
    const float* bt2  = (const float*)d_in[10];
    float* out = (float*)d_out;

    float*          pooled = (float*)d_ws;                          // 8 KiB
    unsigned short* bw     = (unsigned short*)((char*)d_ws + 8192); // 400 KiB bf16 weights

    pool_prep_kernel<<<NB * CIN + 200, 256, 0, stream>>>(x, Wrgb, Wtir, Wt1, pooled, bw);
    dim3 grid(100, NB);
    expert_kernel<<<grid, 256, 0, stream>>>(x, bw, brgb, btir, bt1, Wt2, bt2,
                                            pooled, Wg, bg, out);
}